// Round 5
// baseline (228.516 us; speedup 1.0000x reference)
//
#include <hip/hip_runtime.h>

#define NUMP 53149
#define NROWS (3*NUMP)            // 159447
#define BB 16
#define NK 68
#define HIMG 640
#define WIMG 360
#define NPIX (HIMG*WIMG)          // 230400
#define GS_IDX 26574

// fused kernel geometry: 16 y-tiles of 40 rows
#define YT 16
#define YROWS (HIMG/YT)                // 40
#define TPX (YROWS*WIMG)               // 14400 px per tile
#define TQ (TPX/4)                     // 3600 quads per tile

// workspace offsets (bytes)
#define SPART_OFF 0                    // 256 floats
#define CPART_OFF 1024                 // 256 ints
#define PTS_OFF   2048

// output offsets (floats)
#define O_LK   0
#define O_LK1  1
#define O_LREG 2
#define O_LD   3
#define O_R1   4
#define O_T    148
#define O_PK2  196
#define O_MASK 2372
#define O_PRED (O_MASK + BB*NPIX)

// ---------------- Kernel 1: points0 = mean + pca @ (param*sqrt(var)) ----------------
// 4 threads per row, 2 rows per thread: 10 independent float4 loads in flight.
__global__ void k_points0(const float* __restrict__ mean, const float* __restrict__ pca,
                          const float* __restrict__ variance, const float* __restrict__ param,
                          float* __restrict__ pts0) {
    __shared__ float coef[80];
    int t = threadIdx.x;
    if (t < 80) coef[t] = param[t] * sqrtf(variance[t]);
    __syncthreads();
    int sub = t & 3;
    int r0 = blockIdx.x * 128 + (t >> 2) * 2;
    int r1 = r0 + 1;
    const float* row0 = pca + (size_t)r0 * 80 + sub * 4;
    const float* row1 = row0 + 80;
    float s0 = 0.f, s1 = 0.f;
    if (r0 < NROWS) {
#pragma unroll
        for (int i = 0; i < 5; ++i) {
            float4 v0 = *(const float4*)(row0 + i * 16);
            int c = sub * 4 + i * 16;
            s0 += v0.x * coef[c] + v0.y * coef[c+1] + v0.z * coef[c+2] + v0.w * coef[c+3];
        }
        if (r1 < NROWS) {
#pragma unroll
            for (int i = 0; i < 5; ++i) {
                float4 v1 = *(const float4*)(row1 + i * 16);
                int c = sub * 4 + i * 16;
                s1 += v1.x * coef[c] + v1.y * coef[c+1] + v1.z * coef[c+2] + v1.w * coef[c+3];
            }
        }
    }
    s0 += __shfl_xor(s0, 1); s0 += __shfl_xor(s0, 2);
    s1 += __shfl_xor(s1, 1); s1 += __shfl_xor(s1, 2);
    if (sub == 0 && r0 < NROWS) {
        pts0[r0] = mean[r0] + s0;
        if (r1 < NROWS) pts0[r1] = mean[r1] + s1;
    }
}

// ---------------- Kernel 2: R1, T, pk2, loss_k, loss_k1, loss_reg ----------------
__global__ void k_keypoints(const float* __restrict__ R_in, const float* __restrict__ T_in,
                            const int* __restrict__ key_kp, const float* __restrict__ key_ref,
                            const float* __restrict__ key_side_ref, const float* __restrict__ param,
                            const float* __restrict__ pts0,
                            float* __restrict__ out) {
    __shared__ float R1s[BB][9];
    __shared__ float pk2s[BB*NK*2];
    __shared__ float red[256];
    int t = threadIdx.x;

    if (t < BB) {
        float ax = R_in[t*3+0], ay = R_in[t*3+1], az = R_in[t*3+2];
        float sx = sinf(ax), cx = cosf(ax);
        float sy = sinf(ay), cy = cosf(ay);
        float sz = sinf(az), cz = cosf(az);
        float r00 = cz*cy, r01 = cz*sy*sx - sz*cx, r02 = cz*sy*cx + sz*sx;
        float r10 = sz*cy, r11 = sz*sy*sx + cz*cx, r12 = sz*sy*cx - cz*sx;
        float r20 = -sy,   r21 = cy*sx,            r22 = cy*cx;
        float rv[9] = {r00,r01,r02,r10,r11,r12,r20,r21,r22};
#pragma unroll
        for (int i = 0; i < 9; ++i) {
            R1s[t][i] = rv[i];
            out[O_R1 + t*9 + i] = rv[i];
        }
        out[O_T + t*3+0] = T_in[t*3+0];
        out[O_T + t*3+1] = T_in[t*3+1];
        out[O_T + t*3+2] = T_in[t*3+2];
    }
    __syncthreads();

    for (int idx = t; idx < BB*NK; idx += 256) {
        int b = idx / NK, k = idx % NK;
        int kk = key_kp[k];
        float px = pts0[kk*3+0], py = pts0[kk*3+1], pz = pts0[kk*3+2];
        const float* R = R1s[b];
        float X = px*R[0] + py*R[3] + pz*R[6] + T_in[b*3+0];
        float Y = px*R[1] + py*R[4] + pz*R[7] + T_in[b*3+1];
        float Z = px*R[2] + py*R[5] + pz*R[8] + T_in[b*3+2];
        float zz = -Z;
        float u = (436.16f*X + 179.22f*zz) / zz;
        float v = (436.16f*Y + 320.08f*zz) / zz;
        pk2s[idx*2+0] = u; pk2s[idx*2+1] = v;
        out[O_PK2 + idx*2+0] = u;
        out[O_PK2 + idx*2+1] = v;
    }
    __syncthreads();

    float accK = 0.f;
    for (int idx = t; idx < BB*52; idx += 256) {
        int b = idx / 52, j = idx % 52;
        int ik = (j == 0) ? 8 : (16 + j);
        float dx = pk2s[(b*NK + ik)*2+0] - key_ref[idx*2+0];
        float dy = pk2s[(b*NK + ik)*2+1] - key_ref[idx*2+1];
        accK += dx*dx + dy*dy;
    }
    float accS = 0.f;
    {
        int b = t / 16, j = t % 16;
        int is_ = (j < 8) ? j : (j + 1);
        float dx = pk2s[(b*NK + is_)*2+0] - key_side_ref[t*2+0];
        float dy = pk2s[(b*NK + is_)*2+1] - key_side_ref[t*2+1];
        accS = dx*dx + dy*dy;
    }
    float accR = (t < 80) ? param[t]*param[t] : 0.f;

    red[t] = accK; __syncthreads();
    for (int s = 128; s > 0; s >>= 1) { if (t < s) red[t] += red[t+s]; __syncthreads(); }
    float sK = red[0]; __syncthreads();
    red[t] = accS; __syncthreads();
    for (int s = 128; s > 0; s >>= 1) { if (t < s) red[t] += red[t+s]; __syncthreads(); }
    float sS = red[0]; __syncthreads();
    red[t] = accR; __syncthreads();
    for (int s = 128; s > 0; s >>= 1) { if (t < s) red[t] += red[t+s]; __syncthreads(); }
    float sR = red[0];

    if (t == 0) {
        out[O_LK]   = sK / (float)(BB*52*2);
        out[O_LK1]  = sS / (float)(BB*16*2);
        out[O_LREG] = sR / 80.f;
    }
}

// ---------------- Kernel 3: fused rasterize (LDS occ byte-map) + depth pass ----------------
// grid = (YT, BB). Each block: batch b, image rows [yt*40, yt*40+40).
__global__ void k_fused(const float* __restrict__ pts0, const float* __restrict__ R_in,
                        const float* __restrict__ T_in, const float* __restrict__ refd,
                        const int* __restrict__ dptr,
                        float* __restrict__ mask_out, float* __restrict__ pred_out,
                        float* __restrict__ sum_part, int* __restrict__ cnt_part) {
    __shared__ unsigned char socc[TPX];    // 14.4 KB occupancy byte-map for this tile
    __shared__ float sgs;
    int t = threadIdx.x;
    int yt = blockIdx.x, b = blockIdx.y;
    int y0 = yt * YROWS;

    // zero LDS occ map
    for (int i = t; i < TQ; i += 256) ((unsigned int*)socc)[i] = 0u;

    // per-block (wave-uniform) rotation matrix for batch b
    float ax = R_in[b*3+0], ay = R_in[b*3+1], az = R_in[b*3+2];
    float sx = sinf(ax), cx = cosf(ax);
    float sy = sinf(ay), cy = cosf(ay);
    float sz = sinf(az), cz = cosf(az);
    float R0 = cz*cy, R1 = cz*sy*sx - sz*cx, R2 = cz*sy*cx + sz*sx;
    float R3 = sz*cy, R4 = sz*sy*sx + cz*cx, R5 = sz*sy*cx - cz*sx;
    float R6 = -sy,   R7 = cy*sx,            R8 = cy*cx;
    float T0 = T_in[b*3+0], T1 = T_in[b*3+1], T2 = T_in[b*3+2];
    __syncthreads();

    // transform all points; rasterize those landing in this tile
    for (int n = t; n < NUMP; n += 256) {
        float px = pts0[n*3+0], py = pts0[n*3+1], pz = pts0[n*3+2];
        float X = px*R0 + py*R3 + pz*R6 + T0;
        float Y = px*R1 + py*R4 + pz*R7 + T1;
        float Z = px*R2 + py*R5 + pz*R8 + T2;
        float zz = -Z;
        float u = (436.16f*X + 179.22f*zz) / zz;
        float v = (436.16f*Y + 320.08f*zz) / zz;
        bool m0 = (v >= 0.f) && (v <= (float)(HIMG-1)) && (u >= 0.f) && (u <= (float)(WIMG-1));
        float mf = m0 ? 1.f : 0.f;
        u *= mf; v *= mf;
        int xi = (int)u;
        int yi = (int)v;
        if (n == GS_IDX) sgs = v;
        if (yi >= y0 && yi < y0 + YROWS) socc[(yi - y0)*WIMG + xi] = 1;
    }
    __syncthreads();

    float g = sgs;
    int w = *dptr;
    float dv = (w >= 0 && w < (1 << 23)) ? (float)w : __int_as_float(w);

    // depth pass over this tile's pixels (4 px/thread/iter, 1KB/wave-instruction)
    float lsum = 0.f; int lcnt = 0;
    size_t base = (size_t)b * NPIX + (size_t)y0 * WIMG;
    for (int i = t; i < TQ; i += 256) {
        unsigned ocw = ((const unsigned int*)socc)[i];
        size_t idx = base + (size_t)i * 4;
        float4 rd = make_float4(0.f, 0.f, 0.f, 0.f);
        if (ocw != 0u) rd = *(const float4*)(refd + idx);
        float rdv[4] = {rd.x, rd.y, rd.z, rd.w};
        float mov[4], pov[4];
#pragma unroll
        for (int k = 0; k < 4; ++k) {
            float occf = ((ocw >> (8*k)) & 255u) ? 1.f : 0.f;
            float pred = g * occf, rm = rdv[k] * occf;
            float df = pred - rm, ld = df * df;
            bool mk = (ld < dv) && (ld > 1e-6f) && (pred > 0.f);
            float ldz = ((ld > dv) || (pred < 1e-5f)) ? 0.f : ld;
            mov[k] = mk ? 1.f : 0.f; pov[k] = pred;
            lsum += ldz; lcnt += mk;
        }
        *(float4*)(mask_out + idx) = make_float4(mov[0], mov[1], mov[2], mov[3]);
        *(float4*)(pred_out + idx) = make_float4(pov[0], pov[1], pov[2], pov[3]);
    }

#pragma unroll
    for (int off = 32; off > 0; off >>= 1) {
        lsum += __shfl_down(lsum, off, 64);
        lcnt += __shfl_down(lcnt, off, 64);
    }
    __shared__ float sred[4];
    __shared__ int   cred[4];
    int lane = t & 63, wid = t >> 6;
    if (lane == 0) { sred[wid] = lsum; cred[wid] = lcnt; }
    __syncthreads();
    if (t == 0) {
        sum_part[b * YT + yt] = sred[0] + sred[1] + sred[2] + sred[3];
        cnt_part[b * YT + yt] = cred[0] + cred[1] + cred[2] + cred[3];
    }
}

// ---------------- Kernel 4: final loss_d from 256 partials ----------------
__global__ void k_lossd(const float* __restrict__ sum_part, const int* __restrict__ cnt_part,
                        float* __restrict__ out) {
    __shared__ float red[BB];
    int t = threadIdx.x;
    int b = t >> 4, k = t & 15;
    float s = sum_part[b * YT + k];
    int   c = cnt_part[b * YT + k];
#pragma unroll
    for (int off = 8; off > 0; off >>= 1) {
        s += __shfl_down(s, off, 16);
        c += __shfl_down(c, off, 16);
    }
    if (k == 0) red[b] = s / ((float)c + 1.f);
    __syncthreads();
    if (t == 0) {
        float a = 0.f;
#pragma unroll
        for (int bb = 0; bb < BB; ++bb) a += red[bb];
        out[O_LD] = a / (float)BB;
    }
}

extern "C" void kernel_launch(void* const* d_in, const int* in_sizes, int n_in,
                              void* d_out, int out_size, void* d_ws, size_t ws_size,
                              hipStream_t stream) {
    const float* mean         = (const float*)d_in[0];
    const float* pca          = (const float*)d_in[1];
    const float* variance     = (const float*)d_in[2];
    const float* param        = (const float*)d_in[3];
    const float* R_in         = (const float*)d_in[4];
    const float* T_in         = (const float*)d_in[5];
    const int*   key_kp       = (const int*)d_in[6];
    const float* key_ref      = (const float*)d_in[7];
    const float* key_side_ref = (const float*)d_in[8];
    const float* ref_depth    = (const float*)d_in[9];
    const int*   dptr         = (const int*)d_in[10];

    float* out = (float*)d_out;
    char*  ws  = (char*)d_ws;
    float* sum_part = (float*)(ws + SPART_OFF);
    int*   cnt_part = (int*)(ws + CPART_OFF);
    float* pts0     = (float*)(ws + PTS_OFF);

    k_points0<<<dim3((NROWS + 127) / 128), 256, 0, stream>>>(mean, pca, variance, param, pts0);
    k_keypoints<<<1, 256, 0, stream>>>(R_in, T_in, key_kp, key_ref, key_side_ref, param, pts0, out);
    k_fused<<<dim3(YT, BB), 256, 0, stream>>>(pts0, R_in, T_in, ref_depth, dptr,
                                              out + O_MASK, out + O_PRED, sum_part, cnt_part);
    k_lossd<<<1, 256, 0, stream>>>(sum_part, cnt_part, out);
}

// Round 6
// 144.862 us; speedup vs baseline: 1.5775x; 1.5775x over previous
//
#include <hip/hip_runtime.h>

#define NUMP 53149
#define NROWS (3*NUMP)            // 159447
#define BB 16
#define NK 68
#define HIMG 640
#define WIMG 360
#define NPIX (HIMG*WIMG)          // 230400
#define GS_IDX 26574

// depth kernel geometry: 16 px/thread, interleaved 1KB-contiguous chunks (R4-proven)
#define DPX 16
#define DBLK (256*DPX)                 // 4096 px per block
#define DGX ((NPIX + DBLK - 1)/DBLK)   // 57
#define DTOT (DGX*BB)                  // 912 blocks

// workspace offsets (bytes)
#define OCC_OFF 0
#define OCC_BYTES (BB*NPIX)            // 3,686,400 (memset region)
#define GS_OFF   OCC_BYTES
#define SPART_OFF (GS_OFF + 64)
#define CPART_OFF (SPART_OFF + 4096)   // BB*DGX=912 floats -> 3648B, pad
#define PTS_OFF   (CPART_OFF + 4096)

// output offsets (floats)
#define O_LK   0
#define O_LK1  1
#define O_LREG 2
#define O_LD   3
#define O_R1   4
#define O_T    148
#define O_PK2  196
#define O_MASK 2372
#define O_PRED (O_MASK + BB*NPIX)

// ---------------- Kernel 1: points0 = mean + pca @ (param*sqrt(var)) ----------------
// 4 threads/row, 4 rows/thread -> 20 independent float4 loads in flight per thread.
// Each load instruction covers 16 full 64B lines (4 lanes x 16B contiguous per row).
__global__ __launch_bounds__(256) void k_points0(
        const float* __restrict__ mean, const float* __restrict__ pca,
        const float* __restrict__ variance, const float* __restrict__ param,
        float* __restrict__ pts0) {
    __shared__ float coef[80];
    int t = threadIdx.x;
    if (t < 80) coef[t] = param[t] * sqrtf(variance[t]);
    __syncthreads();
    int sub = t & 3;
    int rid = t >> 2;                   // 0..63
    int rbase = blockIdx.x * 256;       // 256 rows per block
    float s[4] = {0.f, 0.f, 0.f, 0.f};
#pragma unroll
    for (int j = 0; j < 4; ++j) {
        int r = rbase + rid + 64 * j;
        if (r < NROWS) {
            const float* row = pca + (size_t)r * 80 + sub * 4;
#pragma unroll
            for (int i = 0; i < 5; ++i) {
                float4 v = *(const float4*)(row + i * 16);
                int c = sub * 4 + i * 16;
                s[j] += v.x * coef[c] + v.y * coef[c+1] + v.z * coef[c+2] + v.w * coef[c+3];
            }
        }
    }
#pragma unroll
    for (int j = 0; j < 4; ++j) {
        s[j] += __shfl_xor(s[j], 1);
        s[j] += __shfl_xor(s[j], 2);
    }
    if (sub == 0) {
#pragma unroll
        for (int j = 0; j < 4; ++j) {
            int r = rbase + rid + 64 * j;
            if (r < NROWS) pts0[r] = mean[r] + s[j];
        }
    }
}

// ---------------- Kernel 2: scatter (R4-proven): 1 thread = 1 point, 4 batches, grid.y=4 ----------------
__global__ __launch_bounds__(256) void k_scatter(
        const float* __restrict__ pts0, const float* __restrict__ R_in,
        const float* __restrict__ T_in,
        unsigned char* __restrict__ occ, float* __restrict__ gs) {
    __shared__ float Rs[BB][9];
    __shared__ float Ts[BB][3];
    int t = threadIdx.x;
    if (t < BB) {
        float ax = R_in[t*3+0], ay = R_in[t*3+1], az = R_in[t*3+2];
        float sx = sinf(ax), cx = cosf(ax);
        float sy = sinf(ay), cy = cosf(ay);
        float sz = sinf(az), cz = cosf(az);
        Rs[t][0] = cz*cy; Rs[t][1] = cz*sy*sx - sz*cx; Rs[t][2] = cz*sy*cx + sz*sx;
        Rs[t][3] = sz*cy; Rs[t][4] = sz*sy*sx + cz*cx; Rs[t][5] = sz*sy*cx - cz*sx;
        Rs[t][6] = -sy;   Rs[t][7] = cy*sx;            Rs[t][8] = cy*cx;
        Ts[t][0] = T_in[t*3+0]; Ts[t][1] = T_in[t*3+1]; Ts[t][2] = T_in[t*3+2];
    }
    __syncthreads();
    int n = blockIdx.x * 256 + t;
    if (n >= NUMP) return;
    float px = pts0[n*3+0], py = pts0[n*3+1], pz = pts0[n*3+2];
    int b0 = blockIdx.y * 4;
#pragma unroll
    for (int i = 0; i < 4; ++i) {
        int b = b0 + i;
        const float* R = Rs[b];
        float X = px*R[0] + py*R[3] + pz*R[6] + Ts[b][0];
        float Y = px*R[1] + py*R[4] + pz*R[7] + Ts[b][1];
        float Z = px*R[2] + py*R[5] + pz*R[8] + Ts[b][2];
        float zz = -Z;
        float u = (436.16f*X + 179.22f*zz) / zz;
        float v = (436.16f*Y + 320.08f*zz) / zz;
        bool m0 = (v >= 0.f) && (v <= (float)(HIMG-1)) && (u >= 0.f) && (u <= (float)(WIMG-1));
        float mf = m0 ? 1.f : 0.f;
        u *= mf; v *= mf;
        int xi = (int)u;
        int yi = (int)v;
        occ[(size_t)b*NPIX + yi*WIMG + xi] = 1;
        if (n == GS_IDX) gs[b] = v;
    }
}

// ---------------- Kernel 3: depth (R4-proven): 16 px/thread interleaved, no atomics ----------------
__global__ __launch_bounds__(256) void k_depth(
        const unsigned char* __restrict__ occ, const float* __restrict__ refd,
        const float* __restrict__ gs, const int* __restrict__ dptr,
        float* __restrict__ mask_out, float* __restrict__ pred_out,
        float* __restrict__ sum_part, int* __restrict__ cnt_part) {
    int b = blockIdx.y;
    int t = threadIdx.x;
    int blk0 = blockIdx.x * DBLK;
    float g = gs[b];
    int w = *dptr;
    float dv = (w >= 0 && w < (1 << 23)) ? (float)w : __int_as_float(w);

    float lsum = 0.f; int lcnt = 0;
    size_t bbase = (size_t)b * NPIX;
#pragma unroll
    for (int j = 0; j < 4; ++j) {
        int pix = blk0 + j * 1024 + t * 4;
        if (blk0 + j * 1024 >= NPIX) break;   // NPIX multiple of 1024: uniform
        size_t idx = bbase + pix;
        unsigned ocw = *(const unsigned*)(occ + idx);
        float4 rd = make_float4(0.f, 0.f, 0.f, 0.f);
        if (ocw != 0u) rd = *(const float4*)(refd + idx);
        float rdv[4] = {rd.x, rd.y, rd.z, rd.w};
        float mov[4], pov[4];
#pragma unroll
        for (int k = 0; k < 4; ++k) {
            float occf = ((ocw >> (8*k)) & 255u) ? 1.f : 0.f;
            float pred = g * occf, rm = rdv[k] * occf;
            float df = pred - rm, ld = df * df;
            bool mk = (ld < dv) && (ld > 1e-6f) && (pred > 0.f);
            float ldz = ((ld > dv) || (pred < 1e-5f)) ? 0.f : ld;
            mov[k] = mk ? 1.f : 0.f; pov[k] = pred;
            lsum += ldz; lcnt += mk;
        }
        *(float4*)(mask_out + idx) = make_float4(mov[0], mov[1], mov[2], mov[3]);
        *(float4*)(pred_out + idx) = make_float4(pov[0], pov[1], pov[2], pov[3]);
    }

#pragma unroll
    for (int off = 32; off > 0; off >>= 1) {
        lsum += __shfl_down(lsum, off, 64);
        lcnt += __shfl_down(lcnt, off, 64);
    }
    __shared__ float sred[4];
    __shared__ int   cred[4];
    int lane = t & 63, wid = t >> 6;
    if (lane == 0) { sred[wid] = lsum; cred[wid] = lcnt; }
    __syncthreads();
    if (t == 0) {
        sum_part[b * DGX + blockIdx.x] = sred[0] + sred[1] + sred[2] + sred[3];
        cnt_part[b * DGX + blockIdx.x] = cred[0] + cred[1] + cred[2] + cred[3];
    }
}

// ---------------- Kernel 4 (tail): keypoint losses + R1/T/pk2 outputs + loss_d ----------------
__global__ __launch_bounds__(256) void k_tail(
        const float* __restrict__ R_in, const float* __restrict__ T_in,
        const int* __restrict__ key_kp, const float* __restrict__ key_ref,
        const float* __restrict__ key_side_ref, const float* __restrict__ param,
        const float* __restrict__ pts0,
        const float* __restrict__ sum_part, const int* __restrict__ cnt_part,
        float* __restrict__ out) {
    __shared__ float R1s[BB][9];
    __shared__ float pk2s[BB*NK*2];
    __shared__ float red[256];
    int t = threadIdx.x;

    // ---- loss_d from 912 partials ----
    {
        int b = t >> 4, k = t & 15;
        float s = 0.f; int c = 0;
        for (int i = k; i < DGX; i += 16) {
            s += sum_part[b * DGX + i];
            c += cnt_part[b * DGX + i];
        }
#pragma unroll
        for (int off = 8; off > 0; off >>= 1) {
            s += __shfl_down(s, off, 16);
            c += __shfl_down(c, off, 16);
        }
        if (k == 0) red[b] = s / ((float)c + 1.f);
    }
    __syncthreads();
    if (t == 0) {
        float a = 0.f;
#pragma unroll
        for (int bb = 0; bb < BB; ++bb) a += red[bb];
        out[O_LD] = a / (float)BB;
    }
    __syncthreads();

    // ---- keypoint path ----
    if (t < BB) {
        float ax = R_in[t*3+0], ay = R_in[t*3+1], az = R_in[t*3+2];
        float sx = sinf(ax), cx = cosf(ax);
        float sy = sinf(ay), cy = cosf(ay);
        float sz = sinf(az), cz = cosf(az);
        float r00 = cz*cy, r01 = cz*sy*sx - sz*cx, r02 = cz*sy*cx + sz*sx;
        float r10 = sz*cy, r11 = sz*sy*sx + cz*cx, r12 = sz*sy*cx - cz*sx;
        float r20 = -sy,   r21 = cy*sx,            r22 = cy*cx;
        float rv[9] = {r00,r01,r02,r10,r11,r12,r20,r21,r22};
#pragma unroll
        for (int i = 0; i < 9; ++i) {
            R1s[t][i] = rv[i];
            out[O_R1 + t*9 + i] = rv[i];
        }
        out[O_T + t*3+0] = T_in[t*3+0];
        out[O_T + t*3+1] = T_in[t*3+1];
        out[O_T + t*3+2] = T_in[t*3+2];
    }
    __syncthreads();

    for (int idx = t; idx < BB*NK; idx += 256) {
        int b = idx / NK, k = idx % NK;
        int kk = key_kp[k];
        float px = pts0[kk*3+0], py = pts0[kk*3+1], pz = pts0[kk*3+2];
        const float* R = R1s[b];
        float X = px*R[0] + py*R[3] + pz*R[6] + T_in[b*3+0];
        float Y = px*R[1] + py*R[4] + pz*R[7] + T_in[b*3+1];
        float Z = px*R[2] + py*R[5] + pz*R[8] + T_in[b*3+2];
        float zz = -Z;
        float u = (436.16f*X + 179.22f*zz) / zz;
        float v = (436.16f*Y + 320.08f*zz) / zz;
        pk2s[idx*2+0] = u; pk2s[idx*2+1] = v;
        out[O_PK2 + idx*2+0] = u;
        out[O_PK2 + idx*2+1] = v;
    }
    __syncthreads();

    float accK = 0.f;
    for (int idx = t; idx < BB*52; idx += 256) {
        int b = idx / 52, j = idx % 52;
        int ik = (j == 0) ? 8 : (16 + j);
        float dx = pk2s[(b*NK + ik)*2+0] - key_ref[idx*2+0];
        float dy = pk2s[(b*NK + ik)*2+1] - key_ref[idx*2+1];
        accK += dx*dx + dy*dy;
    }
    float accS = 0.f;
    {
        int b = t / 16, j = t % 16;
        int is_ = (j < 8) ? j : (j + 1);
        float dx = pk2s[(b*NK + is_)*2+0] - key_side_ref[t*2+0];
        float dy = pk2s[(b*NK + is_)*2+1] - key_side_ref[t*2+1];
        accS = dx*dx + dy*dy;
    }
    float accR = (t < 80) ? param[t]*param[t] : 0.f;

    red[t] = accK; __syncthreads();
    for (int s = 128; s > 0; s >>= 1) { if (t < s) red[t] += red[t+s]; __syncthreads(); }
    float sK = red[0]; __syncthreads();
    red[t] = accS; __syncthreads();
    for (int s = 128; s > 0; s >>= 1) { if (t < s) red[t] += red[t+s]; __syncthreads(); }
    float sS = red[0]; __syncthreads();
    red[t] = accR; __syncthreads();
    for (int s = 128; s > 0; s >>= 1) { if (t < s) red[t] += red[t+s]; __syncthreads(); }
    float sR = red[0];

    if (t == 0) {
        out[O_LK]   = sK / (float)(BB*52*2);
        out[O_LK1]  = sS / (float)(BB*16*2);
        out[O_LREG] = sR / 80.f;
    }
}

extern "C" void kernel_launch(void* const* d_in, const int* in_sizes, int n_in,
                              void* d_out, int out_size, void* d_ws, size_t ws_size,
                              hipStream_t stream) {
    const float* mean         = (const float*)d_in[0];
    const float* pca          = (const float*)d_in[1];
    const float* variance     = (const float*)d_in[2];
    const float* param        = (const float*)d_in[3];
    const float* R_in         = (const float*)d_in[4];
    const float* T_in         = (const float*)d_in[5];
    const int*   key_kp       = (const int*)d_in[6];
    const float* key_ref      = (const float*)d_in[7];
    const float* key_side_ref = (const float*)d_in[8];
    const float* ref_depth    = (const float*)d_in[9];
    const int*   dptr         = (const int*)d_in[10];

    float* out = (float*)d_out;
    char*  ws  = (char*)d_ws;
    unsigned char* occ = (unsigned char*)(ws + OCC_OFF);
    float* gs       = (float*)(ws + GS_OFF);
    float* sum_part = (float*)(ws + SPART_OFF);
    int*   cnt_part = (int*)(ws + CPART_OFF);
    float* pts0     = (float*)(ws + PTS_OFF);

    (void)hipMemsetAsync(occ, 0, OCC_BYTES, stream);

    k_points0<<<dim3((NROWS + 255) / 256), 256, 0, stream>>>(mean, pca, variance, param, pts0);
    k_scatter<<<dim3((NUMP + 255) / 256, 4), 256, 0, stream>>>(pts0, R_in, T_in, occ, gs);
    k_depth<<<dim3(DGX, BB), 256, 0, stream>>>(occ, ref_depth, gs, dptr,
                                               out + O_MASK, out + O_PRED, sum_part, cnt_part);
    k_tail<<<1, 256, 0, stream>>>(R_in, T_in, key_kp, key_ref, key_side_ref, param, pts0,
                                  sum_part, cnt_part, out);
}